// Round 14
// baseline (41.093 us; speedup 1.0000x reference)
//
#include <hip/hip_runtime.h>

#define DIM 4096

typedef float v2f __attribute__((ext_vector_type(2)));

constexpr float LOG2E = 1.44269504088896340736f;
constexpr float TWO_LOG2E = 2.0f * LOG2E;

__device__ __forceinline__ float fexp2s(float x) { return __builtin_amdgcn_exp2f(x); }
__device__ __forceinline__ float frcps(float x) { return __builtin_amdgcn_rcpf(x); }

// ======================= packed 2-channel (phase 1) =======================
__device__ __forceinline__ v2f expv(v2f u) {
  v2f r; r.x = fexp2s(u.x); r.y = fexp2s(u.y); return r;
}
__device__ __forceinline__ v2f rcpv(v2f u) {
  v2f r; r.x = frcps(u.x); r.y = frcps(u.y); return r;
}
__device__ __forceinline__ v2f fmav(v2f a, v2f b, v2f c) {
  return __builtin_elementwise_fma(a, b, c);   // -> v_pk_fma_f32
}
// e = 2^min(-u, 30): sigma-error <= 2^-30; keeps all fused denominators finite.
__device__ __forceinline__ v2f eclampv(v2f u) {
  v2f c30 = {30.0f, 30.0f};
  return expv(__builtin_elementwise_min(-u, c30));
}

// VALU reciprocal for the h-output divide ONLY (error does not pass through
// an exponential): magic estimate (~4% rel) + 1 packed-Newton -> ~1.6e-3 rel.
// 4 instr, 3-deep chain; removes 2 trans ops/pair from the saturated pipe.
__device__ __forceinline__ float rcp_est(float x) {
  return __int_as_float(0x7EF311C3 - __float_as_int(x));
}
__device__ __forceinline__ v2f rcpv_fast1(v2f x) {
  v2f r; r.x = rcp_est(x.x); r.y = rcp_est(x.y);
  v2f two = {2.0f, 2.0f};
  return r * fmav(-x, r, two);  // Newton 1
}

struct P2pk {
  v2f wf, uf, bf;   // pre-scaled by log2e
  v2f wi, ui, bi;   // pre-scaled by log2e
  v2f wc, uc, bc;   // pre-scaled by 2*log2e  (tanh uses e^{-2z})
  v2f wo, uo, bo;   // pre-scaled by log2e
};

__device__ __forceinline__ v2f ldv(const float* p) { return *(const v2f*)p; }
__device__ __forceinline__ v2f ldscale(const float* p, int d2, float s) {
  return ldv(p + d2) * s;
}

__device__ __forceinline__ P2pk load_params_pk(
    int d2,
    const float* wf, const float* uf, const float* bf,
    const float* wi, const float* ui, const float* bi,
    const float* wc, const float* uc, const float* bc,
    const float* wo, const float* uo, const float* bo) {
  P2pk p;
  p.wf = ldscale(wf, d2, LOG2E);     p.uf = ldscale(uf, d2, LOG2E);     p.bf = ldscale(bf, d2, LOG2E);
  p.wi = ldscale(wi, d2, LOG2E);     p.ui = ldscale(ui, d2, LOG2E);     p.bi = ldscale(bi, d2, LOG2E);
  p.wc = ldscale(wc, d2, TWO_LOG2E); p.uc = ldscale(uc, d2, TWO_LOG2E); p.bc = ldscale(bc, d2, TWO_LOG2E);
  p.wo = ldscale(wo, d2, LOG2E);     p.uo = ldscale(uo, d2, LOG2E);     p.bo = ldscale(bo, d2, LOG2E);
  return p;
}

// Leaf (h_sum = 0): ct exact via trans-rcp; h-divide via 1-Newton VALU rcp.
__device__ __forceinline__ v2f leaf_node_pk(v2f x, const P2pk& p) {
  v2f ef = eclampv(fmav(p.wf, x, p.bf));
  v2f ei = eclampv(fmav(p.wi, x, p.bi));
  v2f eg = eclampv(fmav(p.wc, x, p.bc));
  v2f sf = ef + 1.0f;
  v2f si = ei + 1.0f;
  v2f t1 = fmav(si, eg, si);                    // (1+ei)(1+eg)
  v2f num = fmav(1.0f - eg, sf, t1);
  v2f ct = num * rcpv(t1 * sf);
  v2f eo = eclampv(fmav(p.wo, x, p.bo));
  v2f ec = expv(ct * (-TWO_LOG2E));             // |ct| <= 2 here
  v2f so = eo + 1.0f;
  return (1.0f - ec) * rcpv_fast1(fmav(so, ec, so));
}

// Inner node: ct exact via trans-rcp; h-divide via 1-Newton VALU rcp.
__device__ __forceinline__ v2f inner_node_pk(v2f x, v2f hl, v2f hr, const P2pk& p) {
  v2f hs = hl + hr;
  v2f af = fmav(p.wf, x, p.bf);
  v2f e1 = eclampv(fmav(p.uf, hl, af));
  v2f e2 = eclampv(fmav(p.uf, hr, af));
  v2f s1 = e1 + 1.0f;
  v2f fD = fmav(s1, e2, s1);                    // (1+e1)(1+e2)
  v2f fN = (e1 + e2) + 2.0f;
  v2f ei = eclampv(fmav(p.ui, hs, fmav(p.wi, x, p.bi)));
  v2f eg = eclampv(fmav(p.uc, hs, fmav(p.wc, x, p.bc)));
  v2f si = ei + 1.0f;
  v2f iD = fmav(si, eg, si);                    // (1+ei)(1+eg)
  v2f iN = 1.0f - eg;
  v2f num = fmav(iN, fD, fN * iD);
  v2f ct = num * rcpv(fD * iD);
  v2f eo = eclampv(fmav(p.uo, hs, fmav(p.wo, x, p.bo)));
  v2f ec = expv(ct * (-TWO_LOG2E));             // |ct| <= 3, no clamp needed
  v2f so = eo + 1.0f;
  return (1.0f - ec) * rcpv_fast1(fmav(so, ec, so));
}

// Compile-time-unrolled DFS (minimal live set; no runtime-indexed arrays).
template <int LVL>
__device__ __forceinline__ v2f subtree_h_pk(const float* __restrict__ tvd, int node,
                                            const P2pk& p) {
  if constexpr (LVL == 12) {
    v2f x = ldv(tvd + (size_t)node * DIM);
    return leaf_node_pk(x, p);
  } else {
    v2f hl = subtree_h_pk<LVL + 1>(tvd, 2 * node + 1, p);
    v2f hr = subtree_h_pk<LVL + 1>(tvd, 2 * node + 2, p);
    v2f x = ldv(tvd + (size_t)node * DIM);
    return inner_node_pk(x, hl, hr, p);
  }
}

// Phase 1: 256 subtrees (roots at level 8) x 8 channel-blocks of 512 ch,
// 256 thr/block, 2 channels/thread (packed fp32). Levels 12..8 -> ws.
__global__ __launch_bounds__(256, 6) void treelstm_p1(
    const float* __restrict__ tv,
    const float* __restrict__ wf, const float* __restrict__ uf, const float* __restrict__ bf,
    const float* __restrict__ wi, const float* __restrict__ ui, const float* __restrict__ bi,
    const float* __restrict__ wc, const float* __restrict__ uc, const float* __restrict__ bc,
    const float* __restrict__ wo, const float* __restrict__ uo, const float* __restrict__ bo,
    float* __restrict__ ws) {
  const int cb = blockIdx.x & 7;                 // channel block (512 channels)
  const int g  = blockIdx.x >> 3;                // subtree index 0..255
  const int d2 = cb * 512 + threadIdx.x * 2;     // first of 2 channels
  const float* tvd = tv + d2;

  const P2pk p = load_params_pk(d2, wf, uf, bf, wi, ui, bi, wc, uc, bc, wo, uo, bo);

  const int root = 255 + g;                      // level-8 node
  v2f h = subtree_h_pk<8>(tvd, root, p);
  *(v2f*)&ws[(size_t)g * DIM + d2] = h;
}

// ======================= scalar top-tree (phase 2, fused; exact) =======================
struct Params {
  float wf, uf, bf;
  float wi, ui, bi;
  float wc, uc, bc;
  float wo, uo, bo;
};

__device__ __forceinline__ Params load_params_s(
    int d,
    const float* wf, const float* uf, const float* bf,
    const float* wi, const float* ui, const float* bi,
    const float* wc, const float* uc, const float* bc,
    const float* wo, const float* uo, const float* bo) {
  Params p;
  p.wf = wf[d] * LOG2E;     p.uf = uf[d] * LOG2E;     p.bf = bf[d] * LOG2E;
  p.wi = wi[d] * LOG2E;     p.ui = ui[d] * LOG2E;     p.bi = bi[d] * LOG2E;
  p.wc = wc[d] * TWO_LOG2E; p.uc = uc[d] * TWO_LOG2E; p.bc = bc[d] * TWO_LOG2E;
  p.wo = wo[d] * LOG2E;     p.uo = uo[d] * LOG2E;     p.bo = bo[d] * LOG2E;
  return p;
}

__device__ __forceinline__ float sig_sum2(float u1, float u2) {
  float e1 = fexp2s(-u1);
  float e2 = fexp2s(-u2);
  float s1 = 1.0f + e1;
  float den = fmaf(s1, e2, s1);        // (1+e1)(1+e2)
  float num = (2.0f + e1) + e2;
  return num * frcps(den);
}

__device__ __forceinline__ float sig_mul_tanh(float ui, float ug) {
  float ei = fexp2s(-ui);
  float eg = fexp2s(fminf(-ug, 60.0f));
  float si = 1.0f + ei;
  float den = fmaf(si, eg, si);        // (1+ei)(1+eg)
  float num = 1.0f - eg;
  return num * frcps(den);
}

__device__ __forceinline__ float inner_node_s(float x, float hl, float hr,
                                              const Params& p, float& ct_out) {
  float hs = hl + hr;
  float af = fmaf(p.wf, x, p.bf);
  float fsum = sig_sum2(fmaf(p.uf, hl, af), fmaf(p.uf, hr, af));
  float itgt = sig_mul_tanh(fmaf(p.ui, hs, fmaf(p.wi, x, p.bi)),
                            fmaf(p.uc, hs, fmaf(p.wc, x, p.bc)));
  float ct = itgt + fsum;
  ct_out = ct;
  return sig_mul_tanh(fmaf(p.uo, hs, fmaf(p.wo, x, p.bo)), ct * TWO_LOG2E);
}

// Breadth-ILP sub-tree: global level LVL down to staged level SPLIT.
template <int SPLIT, int LVL>
__device__ __forceinline__ float top_h(const float* __restrict__ tvd,
                                       const float* __restrict__ hind, int node,
                                       const Params& p, float& ct_out) {
  if constexpr (LVL == SPLIT) {
    ct_out = 0.0f;  // never consumed at this level
    return hind[(size_t)(node - ((1 << SPLIT) - 1)) * DIM];
  } else {
    float cl, cr;
    float hl = top_h<SPLIT, LVL + 1>(tvd, hind, 2 * node + 1, p, cl);
    float hr = top_h<SPLIT, LVL + 1>(tvd, hind, 2 * node + 2, p, cr);
    float x = tvd[(size_t)node * DIM];
    return inner_node_s(x, hl, hr, p, ct_out);
  }
}

// Fused phase 2: levels 7..0. 256 blocks x 256 threads.
__global__ __launch_bounds__(256) void treelstm_top(
    const float* __restrict__ tv,
    const float* __restrict__ wf, const float* __restrict__ uf, const float* __restrict__ bf,
    const float* __restrict__ wi, const float* __restrict__ ui, const float* __restrict__ bi,
    const float* __restrict__ wc, const float* __restrict__ uc, const float* __restrict__ bc,
    const float* __restrict__ wo, const float* __restrict__ uo, const float* __restrict__ bo,
    const float* __restrict__ A, float* __restrict__ out) {
  __shared__ float h4[16][17];
  __shared__ float h3[8][17];
  __shared__ float h2[4][17];
  __shared__ float h1[2][17];

  const int t  = threadIdx.x;
  const int j  = t >> 4;                  // 0..15
  const int dl = t & 15;                  // 0..15
  const int d  = blockIdx.x * 16 + dl;    // channel

  const Params p = load_params_s(d, wf, uf, bf, wi, ui, bi, wc, uc, bc, wo, uo, bo);

  // ---- levels 7..4: L4-tree j (global node 15+j), staged input at level 8 ----
  float ct;
  h4[j][dl] = top_h<8, 4>(tv + d, A + d, 15 + j, p, ct);
  __syncthreads();

  // ---- level 3: nodes 7..14 ----
  if (j < 8) {
    float x = tv[(size_t)(7 + j) * DIM + d];
    h3[j][dl] = inner_node_s(x, h4[2 * j][dl], h4[2 * j + 1][dl], p, ct);
  }
  __syncthreads();

  // ---- level 2: nodes 3..6 ----
  if (j < 4) {
    float x = tv[(size_t)(3 + j) * DIM + d];
    h2[j][dl] = inner_node_s(x, h3[2 * j][dl], h3[2 * j + 1][dl], p, ct);
  }
  __syncthreads();

  // ---- level 1: nodes 1..2 ----
  if (j < 2) {
    float x = tv[(size_t)(1 + j) * DIM + d];
    h1[j][dl] = inner_node_s(x, h2[2 * j][dl], h2[2 * j + 1][dl], p, ct);
  }
  __syncthreads();

  // ---- level 0: root ----
  if (j == 0) {
    float x = tv[d];
    float h = inner_node_s(x, h1[0][dl], h1[1][dl], p, ct);
    out[d] = h;
    out[DIM + d] = ct;
  }
}

extern "C" void kernel_launch(void* const* d_in, const int* in_sizes, int n_in,
                              void* d_out, int out_size, void* d_ws, size_t ws_size,
                              hipStream_t stream) {
  const float* tv = (const float*)d_in[0];
  // d_in[1] = depth (int, 13) -- structure hard-coded to depth 13.
  const float* wf = (const float*)d_in[2];
  const float* uf = (const float*)d_in[3];
  const float* bf = (const float*)d_in[4];
  const float* wi = (const float*)d_in[5];
  const float* ui = (const float*)d_in[6];
  const float* bi = (const float*)d_in[7];
  const float* wc = (const float*)d_in[8];
  const float* uc = (const float*)d_in[9];
  const float* bc = (const float*)d_in[10];
  const float* wo = (const float*)d_in[11];
  const float* uo = (const float*)d_in[12];
  const float* bo = (const float*)d_in[13];

  float* out = (float*)d_out;                   // 8192 floats: h then c
  float* A = (float*)d_ws;                      // 256 level-8 h rows (4 MiB)

  // Phase 1: levels 12..8 fused in registers -> A.
  treelstm_p1<<<dim3(256 * 8), dim3(256), 0, stream>>>(
      tv, wf, uf, bf, wi, ui, bi, wc, uc, bc, wo, uo, bo, A);

  // Phase 2 (fused): levels 7..0 -> out.
  treelstm_top<<<dim3(256), dim3(256), 0, stream>>>(
      tv, wf, uf, bf, wi, ui, bi, wc, uc, bc, wo, uo, bo, A, out);
}

// Round 15
// 40.744 us; speedup vs baseline: 1.0086x; 1.0086x over previous
//
#include <hip/hip_runtime.h>

#define DIM 4096

typedef float v2f __attribute__((ext_vector_type(2)));

constexpr float LOG2E = 1.44269504088896340736f;
constexpr float TWO_LOG2E = 2.0f * LOG2E;

__device__ __forceinline__ float fexp2s(float x) { return __builtin_amdgcn_exp2f(x); }
__device__ __forceinline__ float frcps(float x) { return __builtin_amdgcn_rcpf(x); }

// ======================= packed 2-channel (phase 1) =======================
// (byte-identical to round 11/13's best-known p1: exact math, trans-rcp)
__device__ __forceinline__ v2f expv(v2f u) {
  v2f r; r.x = fexp2s(u.x); r.y = fexp2s(u.y); return r;
}
__device__ __forceinline__ v2f rcpv(v2f u) {
  v2f r; r.x = frcps(u.x); r.y = frcps(u.y); return r;
}
__device__ __forceinline__ v2f fmav(v2f a, v2f b, v2f c) {
  return __builtin_elementwise_fma(a, b, c);   // -> v_pk_fma_f32
}
// e = 2^min(-u, 30): sigma-error <= 2^-30; keeps all fused denominators finite.
__device__ __forceinline__ v2f eclampv(v2f u) {
  v2f c30 = {30.0f, 30.0f};
  return expv(__builtin_elementwise_min(-u, c30));
}

struct P2pk {
  v2f wf, uf, bf;   // pre-scaled by log2e
  v2f wi, ui, bi;   // pre-scaled by log2e
  v2f wc, uc, bc;   // pre-scaled by 2*log2e  (tanh uses e^{-2z})
  v2f wo, uo, bo;   // pre-scaled by log2e
};

__device__ __forceinline__ v2f ldv(const float* p) { return *(const v2f*)p; }
__device__ __forceinline__ v2f ldscale(const float* p, int d2, float s) {
  return ldv(p + d2) * s;
}

__device__ __forceinline__ P2pk load_params_pk(
    int d2,
    const float* wf, const float* uf, const float* bf,
    const float* wi, const float* ui, const float* bi,
    const float* wc, const float* uc, const float* bc,
    const float* wo, const float* uo, const float* bo) {
  P2pk p;
  p.wf = ldscale(wf, d2, LOG2E);     p.uf = ldscale(uf, d2, LOG2E);     p.bf = ldscale(bf, d2, LOG2E);
  p.wi = ldscale(wi, d2, LOG2E);     p.ui = ldscale(ui, d2, LOG2E);     p.bi = ldscale(bi, d2, LOG2E);
  p.wc = ldscale(wc, d2, TWO_LOG2E); p.uc = ldscale(uc, d2, TWO_LOG2E); p.bc = ldscale(bc, d2, TWO_LOG2E);
  p.wo = ldscale(wo, d2, LOG2E);     p.uo = ldscale(uo, d2, LOG2E);     p.bo = ldscale(bo, d2, LOG2E);
  return p;
}

// Leaf (h_sum = 0), exact: ct = [ (1-eg)(1+ef) + (1+ei)(1+eg) ] / [ (1+ef)(1+ei)(1+eg) ]
__device__ __forceinline__ v2f leaf_node_pk(v2f x, const P2pk& p) {
  v2f ef = eclampv(fmav(p.wf, x, p.bf));
  v2f ei = eclampv(fmav(p.wi, x, p.bi));
  v2f eg = eclampv(fmav(p.wc, x, p.bc));
  v2f sf = ef + 1.0f;
  v2f si = ei + 1.0f;
  v2f t1 = fmav(si, eg, si);                    // (1+ei)(1+eg)
  v2f num = fmav(1.0f - eg, sf, t1);
  v2f ct = num * rcpv(t1 * sf);
  v2f eo = eclampv(fmav(p.wo, x, p.bo));
  v2f ec = expv(ct * (-TWO_LOG2E));             // |ct| <= 2 here
  v2f so = eo + 1.0f;
  return (1.0f - ec) * rcpv(fmav(so, ec, so));
}

// Inner node, fused single-rcp ct (exact up to 2^-30 clamps).
__device__ __forceinline__ v2f inner_node_pk(v2f x, v2f hl, v2f hr, const P2pk& p) {
  v2f hs = hl + hr;
  v2f af = fmav(p.wf, x, p.bf);
  v2f e1 = eclampv(fmav(p.uf, hl, af));
  v2f e2 = eclampv(fmav(p.uf, hr, af));
  v2f s1 = e1 + 1.0f;
  v2f fD = fmav(s1, e2, s1);                    // (1+e1)(1+e2)
  v2f fN = (e1 + e2) + 2.0f;
  v2f ei = eclampv(fmav(p.ui, hs, fmav(p.wi, x, p.bi)));
  v2f eg = eclampv(fmav(p.uc, hs, fmav(p.wc, x, p.bc)));
  v2f si = ei + 1.0f;
  v2f iD = fmav(si, eg, si);                    // (1+ei)(1+eg)
  v2f iN = 1.0f - eg;
  v2f num = fmav(iN, fD, fN * iD);
  v2f ct = num * rcpv(fD * iD);
  v2f eo = eclampv(fmav(p.uo, hs, fmav(p.wo, x, p.bo)));
  v2f ec = expv(ct * (-TWO_LOG2E));             // |ct| <= 3, no clamp needed
  v2f so = eo + 1.0f;
  return (1.0f - ec) * rcpv(fmav(so, ec, so));
}

// Compile-time-unrolled DFS (minimal live set; no runtime-indexed arrays).
template <int LVL>
__device__ __forceinline__ v2f subtree_h_pk(const float* __restrict__ tvd, int node,
                                            const P2pk& p) {
  if constexpr (LVL == 12) {
    v2f x = ldv(tvd + (size_t)node * DIM);
    return leaf_node_pk(x, p);
  } else {
    v2f hl = subtree_h_pk<LVL + 1>(tvd, 2 * node + 1, p);
    v2f hr = subtree_h_pk<LVL + 1>(tvd, 2 * node + 2, p);
    v2f x = ldv(tvd + (size_t)node * DIM);
    return inner_node_pk(x, hl, hr, p);
  }
}

// Phase 1: 256 subtrees (roots at level 8) x 8 channel-blocks of 512 ch,
// 256 thr/block, 2 channels/thread (packed fp32). Levels 12..8 -> ws.
__global__ __launch_bounds__(256, 6) void treelstm_p1(
    const float* __restrict__ tv,
    const float* __restrict__ wf, const float* __restrict__ uf, const float* __restrict__ bf,
    const float* __restrict__ wi, const float* __restrict__ ui, const float* __restrict__ bi,
    const float* __restrict__ wc, const float* __restrict__ uc, const float* __restrict__ bc,
    const float* __restrict__ wo, const float* __restrict__ uo, const float* __restrict__ bo,
    float* __restrict__ ws) {
  const int cb = blockIdx.x & 7;                 // channel block (512 channels)
  const int g  = blockIdx.x >> 3;                // subtree index 0..255
  const int d2 = cb * 512 + threadIdx.x * 2;     // first of 2 channels
  const float* tvd = tv + d2;

  const P2pk p = load_params_pk(d2, wf, uf, bf, wi, ui, bi, wc, uc, bc, wo, uo, bo);

  const int root = 255 + g;                      // level-8 node
  v2f h = subtree_h_pk<8>(tvd, root, p);
  *(v2f*)&ws[(size_t)g * DIM + d2] = h;
}

// ======================= scalar top-tree (phase 2, fused; exact) =======================
struct Params {
  float wf, uf, bf;
  float wi, ui, bi;
  float wc, uc, bc;
  float wo, uo, bo;
};

__device__ __forceinline__ Params load_params_s(
    int d,
    const float* wf, const float* uf, const float* bf,
    const float* wi, const float* ui, const float* bi,
    const float* wc, const float* uc, const float* bc,
    const float* wo, const float* uo, const float* bo) {
  Params p;
  p.wf = wf[d] * LOG2E;     p.uf = uf[d] * LOG2E;     p.bf = bf[d] * LOG2E;
  p.wi = wi[d] * LOG2E;     p.ui = ui[d] * LOG2E;     p.bi = bi[d] * LOG2E;
  p.wc = wc[d] * TWO_LOG2E; p.uc = uc[d] * TWO_LOG2E; p.bc = bc[d] * TWO_LOG2E;
  p.wo = wo[d] * LOG2E;     p.uo = uo[d] * LOG2E;     p.bo = bo[d] * LOG2E;
  return p;
}

__device__ __forceinline__ float sig_sum2(float u1, float u2) {
  float e1 = fexp2s(-u1);
  float e2 = fexp2s(-u2);
  float s1 = 1.0f + e1;
  float den = fmaf(s1, e2, s1);        // (1+e1)(1+e2)
  float num = (2.0f + e1) + e2;
  return num * frcps(den);
}

__device__ __forceinline__ float sig_mul_tanh(float ui, float ug) {
  float ei = fexp2s(-ui);
  float eg = fexp2s(fminf(-ug, 60.0f));
  float si = 1.0f + ei;
  float den = fmaf(si, eg, si);        // (1+ei)(1+eg)
  float num = 1.0f - eg;
  return num * frcps(den);
}

__device__ __forceinline__ float inner_node_s(float x, float hl, float hr,
                                              const Params& p, float& ct_out) {
  float hs = hl + hr;
  float af = fmaf(p.wf, x, p.bf);
  float fsum = sig_sum2(fmaf(p.uf, hl, af), fmaf(p.uf, hr, af));
  float itgt = sig_mul_tanh(fmaf(p.ui, hs, fmaf(p.wi, x, p.bi)),
                            fmaf(p.uc, hs, fmaf(p.wc, x, p.bc)));
  float ct = itgt + fsum;
  ct_out = ct;
  return sig_mul_tanh(fmaf(p.uo, hs, fmaf(p.wo, x, p.bo)), ct * TWO_LOG2E);
}

// Breadth-ILP sub-tree: global level LVL down to staged level SPLIT.
template <int SPLIT, int LVL>
__device__ __forceinline__ float top_h(const float* __restrict__ tvd,
                                       const float* __restrict__ hind, int node,
                                       const Params& p, float& ct_out) {
  if constexpr (LVL == SPLIT) {
    ct_out = 0.0f;  // never consumed at this level
    return hind[(size_t)(node - ((1 << SPLIT) - 1)) * DIM];
  } else {
    float cl, cr;
    float hl = top_h<SPLIT, LVL + 1>(tvd, hind, 2 * node + 1, p, cl);
    float hr = top_h<SPLIT, LVL + 1>(tvd, hind, 2 * node + 2, p, cr);
    float x = tvd[(size_t)node * DIM];
    return inner_node_s(x, hl, hr, p, ct_out);
  }
}

// Fused phase 2: levels 7..0. 256 blocks x 256 threads.
// Block b owns channels [16b, 16b+16); thread = (j = t>>4 in 0..15, dl = t&15).
__global__ __launch_bounds__(256) void treelstm_top(
    const float* __restrict__ tv,
    const float* __restrict__ wf, const float* __restrict__ uf, const float* __restrict__ bf,
    const float* __restrict__ wi, const float* __restrict__ ui, const float* __restrict__ bi,
    const float* __restrict__ wc, const float* __restrict__ uc, const float* __restrict__ bc,
    const float* __restrict__ wo, const float* __restrict__ uo, const float* __restrict__ bo,
    const float* __restrict__ A, float* __restrict__ out) {
  __shared__ float h4[16][17];
  __shared__ float h3[8][17];
  __shared__ float h2[4][17];
  __shared__ float h1[2][17];

  const int t  = threadIdx.x;
  const int j  = t >> 4;                  // 0..15
  const int dl = t & 15;                  // 0..15
  const int d  = blockIdx.x * 16 + dl;    // channel

  const Params p = load_params_s(d, wf, uf, bf, wi, ui, bi, wc, uc, bc, wo, uo, bo);

  // ---- levels 7..4: L4-tree j (global node 15+j), staged input at level 8 ----
  float ct;
  h4[j][dl] = top_h<8, 4>(tv + d, A + d, 15 + j, p, ct);
  __syncthreads();

  // ---- level 3: nodes 7..14 ----
  if (j < 8) {
    float x = tv[(size_t)(7 + j) * DIM + d];
    h3[j][dl] = inner_node_s(x, h4[2 * j][dl], h4[2 * j + 1][dl], p, ct);
  }
  __syncthreads();

  // ---- level 2: nodes 3..6 ----
  if (j < 4) {
    float x = tv[(size_t)(3 + j) * DIM + d];
    h2[j][dl] = inner_node_s(x, h3[2 * j][dl], h3[2 * j + 1][dl], p, ct);
  }
  __syncthreads();

  // ---- level 1: nodes 1..2 ----
  if (j < 2) {
    float x = tv[(size_t)(1 + j) * DIM + d];
    h1[j][dl] = inner_node_s(x, h2[2 * j][dl], h2[2 * j + 1][dl], p, ct);
  }
  __syncthreads();

  // ---- level 0: root ----
  if (j == 0) {
    float x = tv[d];
    float h = inner_node_s(x, h1[0][dl], h1[1][dl], p, ct);
    out[d] = h;
    out[DIM + d] = ct;
  }
}

extern "C" void kernel_launch(void* const* d_in, const int* in_sizes, int n_in,
                              void* d_out, int out_size, void* d_ws, size_t ws_size,
                              hipStream_t stream) {
  const float* tv = (const float*)d_in[0];
  // d_in[1] = depth (int, 13) -- structure hard-coded to depth 13.
  const float* wf = (const float*)d_in[2];
  const float* uf = (const float*)d_in[3];
  const float* bf = (const float*)d_in[4];
  const float* wi = (const float*)d_in[5];
  const float* ui = (const float*)d_in[6];
  const float* bi = (const float*)d_in[7];
  const float* wc = (const float*)d_in[8];
  const float* uc = (const float*)d_in[9];
  const float* bc = (const float*)d_in[10];
  const float* wo = (const float*)d_in[11];
  const float* uo = (const float*)d_in[12];
  const float* bo = (const float*)d_in[13];

  float* out = (float*)d_out;                   // 8192 floats: h then c
  float* A = (float*)d_ws;                      // 256 level-8 h rows (4 MiB)

  // Phase 1: levels 12..8 fused in registers -> A.
  treelstm_p1<<<dim3(256 * 8), dim3(256), 0, stream>>>(
      tv, wf, uf, bf, wi, ui, bi, wc, uc, bc, wo, uo, bo, A);

  // Phase 2 (fused): levels 7..0 -> out.
  treelstm_top<<<dim3(256), dim3(256), 0, stream>>>(
      tv, wf, uf, bf, wi, ui, bi, wc, uc, bc, wo, uo, bo, A, out);
}